// Round 7
// baseline (468.167 us; speedup 1.0000x reference)
//
#include <hip/hip_runtime.h>

typedef __attribute__((ext_vector_type(8))) short short8;
typedef __attribute__((ext_vector_type(4))) short short4v;
typedef __attribute__((ext_vector_type(4))) float f32x4;
typedef unsigned int u32;

#define AS1 __attribute__((address_space(1)))
#define AS3 __attribute__((address_space(3)))

__device__ __forceinline__ short f2bf(float x){
  union { float f; u32 u; } v; v.f = x;
  u32 r = (v.u + 0x7FFFu + ((v.u >> 16) & 1u)) >> 16;   // RNE
  return (short)r;
}
__device__ __forceinline__ float bf2f(short s){
  union { u32 u; float f; } v; v.u = ((u32)(unsigned short)s) << 16;
  return v.f;
}
__device__ __forceinline__ void gload16(const void* src, void* dst){
  __builtin_amdgcn_global_load_lds((const AS1 u32*)src, (AS3 u32*)dst, 16, 0, 0);
}
#define MFMA_(a,b,c) c = __builtin_amdgcn_mfma_f32_16x16x32_bf16(a, b, c, 0, 0, 0)

// ---------------- converts ----------------
__global__ __launch_bounds__(256) void cvt_x_kernel(const float* __restrict__ x, short* __restrict__ xb){
  int i = blockIdx.x * 256 + threadIdx.x;
  if (i >= 2097152) return;
  const float4* xf = (const float4*)x;
  float4 a = xf[2*i], b = xf[2*i+1];
  short8 o;
  o[0]=f2bf(a.x); o[1]=f2bf(a.y); o[2]=f2bf(a.z); o[3]=f2bf(a.w);
  o[4]=f2bf(b.x); o[5]=f2bf(b.y); o[6]=f2bf(b.z); o[7]=f2bf(b.w);
  ((short8*)xb)[i] = o;
}

// transpose-convert W [K=1024][N=1024] f32 -> Wt [N][K] bf16, z selects q/k/v
__global__ __launch_bounds__(256) void cvt_w_kernel(const float* __restrict__ Wq, const float* __restrict__ Wk,
                                                    const float* __restrict__ Wv, short* __restrict__ Wt){
  __shared__ float tile[32][33];
  const float* W = blockIdx.z == 0 ? Wq : (blockIdx.z == 1 ? Wk : Wv);
  short* out = Wt + (size_t)blockIdx.z * 1024 * 1024;
  int n0 = blockIdx.x * 32, k0 = blockIdx.y * 32;
  int tx = threadIdx.x, ty = threadIdx.y;
  #pragma unroll
  for (int i=0;i<4;i++) tile[ty + 8*i][tx] = W[(size_t)(k0 + ty + 8*i) * 1024 + n0 + tx];
  __syncthreads();
  #pragma unroll
  for (int i=0;i<4;i++) out[(size_t)(n0 + ty + 8*i) * 1024 + k0 + tx] = f2bf(tile[tx][ty + 8*i]);
}

// ---------------- 256x256 8-phase BT-form bf16 GEMM (m201 template) ----------------
// C[m][n] = sum_k A[m][k]*B[n][k].  BK=64, 512 thr = 8 waves (2M x 4N),
// per-wave 128x64 output = acc[8][4] f32x4.  LDS 128 KiB = 2dbuf x 2half x 128x64 x {A,B}.
// Per K-tile: 4 phases, each {ds_read subtile | stage 1 half-tile -> barrier ->
// lgkm(0) -> 16 MFMA (quadrant = i-half x j-half x K64) -> barrier}.
// ds_reads/phase: 12,4,8,0.  Half-tile ring: T+1.{A1,B0,B1} staged P1-P3 (other dbuf),
// T+2.A0 at P4 (cur dbuf; all cur-dbuf reads drained by P3 lgkm0+barrier).
// vmcnt(2) once/tile at P4: drains all 4 halves of T+1, leaves T+2.A0 in flight.
// T1 XCD swizzle, T2 both-sides swizzle (rule #21), T5 setprio.
template<int EPI>
__global__ __launch_bounds__(512, 2)
void gemm256(const short* __restrict__ A, int lda, long abst,
             const short* __restrict__ B, int ldb, long bbst,
             void* __restrict__ Cv, long cbst,
             const float* __restrict__ bias0, const float* __restrict__ bias1,
             int M, int N, int K, float scale)
{
  __shared__ alignas(16) short As[32768];   // [dbuf][half][128][64] bf16
  __shared__ alignas(16) short Bs[32768];

  // T1: XCD swizzle — contiguous work chunks per XCD (nwg % 8 == 0 by launch)
  const u32 nx = gridDim.x, ny = gridDim.y;
  const u32 id  = blockIdx.x + nx * (blockIdx.y + ny * blockIdx.z);
  const u32 nwg = nx * ny * gridDim.z;
  const u32 id2 = (id & 7) * (nwg >> 3) + (id >> 3);
  const u32 bx = id2 % nx;
  const u32 rem = id2 / nx;
  const u32 by = rem % ny;
  const u32 z  = rem / ny;

  A += (size_t)z * abst;
  B += (size_t)z * bbst;
  const int m0 = bx * 256, n0 = by * 256;
  const int tid = threadIdx.x;
  const int w = tid >> 6, l = tid & 63;
  const int wm = w >> 2, wn = w & 3;            // wave grid 2M x 4N
  const int lr = l & 15, l4 = l >> 4;
  const u32 koff0 = ((u32)l4 << 4) ^ ((u32)(l & 7) << 4);  // k-pos ^ row-swizzle
  const u32 koff1 = koff0 ^ 64u;
  const size_t lda2 = (size_t)lda * 2, ldb2 = (size_t)ldb * 2;

  f32x4 acc[8][4];
  #pragma unroll
  for (int i=0;i<8;i++)
    #pragma unroll
    for (int j=0;j<4;j++) acc[i][j] = (f32x4){0.f,0.f,0.f,0.f};

  // staging bases: thread t covers chunk c = i*512+t of a 16KB half-tile;
  // row-in-half = i*64 + (t>>3), chunk = (t&7) ^ (row&7)  [T2 inverse swizzle]
  const int c8 = (tid & 7) ^ ((tid >> 3) & 7);
  const char* ASrcB = (const char*)A + (size_t)(m0 + (tid >> 3)) * lda2 + c8 * 16;
  const char* BSrcB = (const char*)B + (size_t)(n0 + (tid >> 3)) * ldb2 + c8 * 16;
  char* dstA0 = (char*)As + tid * 16;
  char* dstB0 = (char*)Bs + tid * 16;

  const int NT = K >> 6;

  auto stA = [&](int tile, int h){
    const char* s = ASrcB + (size_t)(h * 128) * lda2 + (size_t)tile * 128;
    char* dd = dstA0 + ((tile & 1) * 2 + h) * 16384;
    gload16(s,             dd);
    gload16(s + 64 * lda2, dd + 8192);
  };
  auto stB = [&](int tile, int h){
    const char* s = BSrcB + (size_t)(h * 128) * ldb2 + (size_t)tile * 128;
    char* dd = dstB0 + ((tile & 1) * 2 + h) * 16384;
    gload16(s,             dd);
    gload16(s + 64 * ldb2, dd + 8192);
  };

  // prologue: tile0 all 4 halves + tile1.A0; leave tile1.A0 in flight
  stA(0,0); stA(0,1); stB(0,0); stB(0,1);
  if (NT > 1){ stA(1,0); asm volatile("s_waitcnt vmcnt(2)" ::: "memory"); }
  else       {           asm volatile("s_waitcnt vmcnt(0)" ::: "memory"); }
  __builtin_amdgcn_s_barrier();

  for (int T = 0; T < NT; T++){
    const int d = T & 1;
    const char* aB = (const char*)As + (d*2 + wm) * 16384 + lr * 128;
    const char* bB = (const char*)Bs + (d*2 + (wn >> 1)) * 16384 + ((wn & 1) * 64 + lr) * 128;
    short8 fa0[4], fa1[4], fb0[4], fb1[4];

    // ---- P1: read fa(ih0) 8 + fb(jh0) 4; stage T+1.A1; MFMA (ih0 x jh0) ----
    #pragma unroll
    for (int ii=0; ii<4; ii++){
      fa0[ii] = *(const short8*)(aB + ii*2048 + koff0);
      fa1[ii] = *(const short8*)(aB + ii*2048 + koff1);
    }
    fb0[0] = *(const short8*)(bB + koff0);        fb1[0] = *(const short8*)(bB + koff1);
    fb0[1] = *(const short8*)(bB + 2048 + koff0); fb1[1] = *(const short8*)(bB + 2048 + koff1);
    if (T + 1 < NT) stA(T+1, 1);
    asm volatile("s_waitcnt lgkmcnt(8)" ::: "memory");
    __builtin_amdgcn_s_barrier();
    asm volatile("s_waitcnt lgkmcnt(0)" ::: "memory");
    __builtin_amdgcn_sched_barrier(0);
    __builtin_amdgcn_s_setprio(1);
    #pragma unroll
    for (int ii=0; ii<4; ii++){
      MFMA_(fa0[ii], fb0[0], acc[ii][0]);  MFMA_(fa1[ii], fb1[0], acc[ii][0]);
      MFMA_(fa0[ii], fb0[1], acc[ii][1]);  MFMA_(fa1[ii], fb1[1], acc[ii][1]);
    }
    __builtin_amdgcn_s_setprio(0);
    __builtin_amdgcn_s_barrier();

    // ---- P2: read fb(jh1) 4; stage T+1.B0; MFMA (ih0 x jh1) ----
    fb0[2] = *(const short8*)(bB + 2*2048 + koff0); fb1[2] = *(const short8*)(bB + 2*2048 + koff1);
    fb0[3] = *(const short8*)(bB + 3*2048 + koff0); fb1[3] = *(const short8*)(bB + 3*2048 + koff1);
    if (T + 1 < NT) stB(T+1, 0);
    __builtin_amdgcn_s_barrier();
    asm volatile("s_waitcnt lgkmcnt(0)" ::: "memory");
    __builtin_amdgcn_sched_barrier(0);
    __builtin_amdgcn_s_setprio(1);
    #pragma unroll
    for (int ii=0; ii<4; ii++){
      MFMA_(fa0[ii], fb0[2], acc[ii][2]);  MFMA_(fa1[ii], fb1[2], acc[ii][2]);
      MFMA_(fa0[ii], fb0[3], acc[ii][3]);  MFMA_(fa1[ii], fb1[3], acc[ii][3]);
    }
    __builtin_amdgcn_s_setprio(0);
    __builtin_amdgcn_s_barrier();

    // ---- P3: read fa(ih1) 8 (reuse regs); stage T+1.B1; MFMA (ih1 x jh1) ----
    #pragma unroll
    for (int ii=0; ii<4; ii++){
      fa0[ii] = *(const short8*)(aB + 8192 + ii*2048 + koff0);
      fa1[ii] = *(const short8*)(aB + 8192 + ii*2048 + koff1);
    }
    if (T + 1 < NT) stB(T+1, 1);
    __builtin_amdgcn_s_barrier();
    asm volatile("s_waitcnt lgkmcnt(0)" ::: "memory");
    __builtin_amdgcn_sched_barrier(0);
    __builtin_amdgcn_s_setprio(1);
    #pragma unroll
    for (int ii=0; ii<4; ii++){
      MFMA_(fa0[ii], fb0[2], acc[4+ii][2]);  MFMA_(fa1[ii], fb1[2], acc[4+ii][2]);
      MFMA_(fa0[ii], fb0[3], acc[4+ii][3]);  MFMA_(fa1[ii], fb1[3], acc[4+ii][3]);
    }
    __builtin_amdgcn_s_setprio(0);
    __builtin_amdgcn_s_barrier();

    // ---- P4: no reads; stage T+2.A0 (cur dbuf, now dead); counted vmcnt; MFMA (ih1 x jh0) ----
    if (T + 2 < NT){ stA(T+2, 0); asm volatile("s_waitcnt vmcnt(2)" ::: "memory"); }
    else           {             asm volatile("s_waitcnt vmcnt(0)" ::: "memory"); }
    __builtin_amdgcn_s_barrier();
    __builtin_amdgcn_sched_barrier(0);
    __builtin_amdgcn_s_setprio(1);
    #pragma unroll
    for (int ii=0; ii<4; ii++){
      MFMA_(fa0[ii], fb0[0], acc[4+ii][0]);  MFMA_(fa1[ii], fb1[0], acc[4+ii][0]);
      MFMA_(fa0[ii], fb0[1], acc[4+ii][1]);  MFMA_(fa1[ii], fb1[1], acc[4+ii][1]);
    }
    __builtin_amdgcn_s_setprio(0);
    __builtin_amdgcn_s_barrier();
  }

  // epilogue: C/D layout col = lane&15, row = (lane>>4)*4 + reg  [m89/m91]
  const int mwb = m0 + wm*128 + l4*4;
  const int nwb = n0 + wn*64 + lr;

  if constexpr (EPI == 0){
    const float* bias = z ? bias1 : bias0;
    short* C = (short*)Cv + (size_t)z * cbst;
    float bvv[4];
    #pragma unroll
    for (int j=0;j<4;j++) bvv[j] = bias[nwb + j*16];
    #pragma unroll
    for (int i=0;i<8;i++){
      int m = mwb + i*16;
      #pragma unroll
      for (int j=0;j<4;j++){
        int n = nwb + j*16;
        #pragma unroll
        for (int r=0;r<4;r++)
          C[(size_t)(m+r)*N + n] = f2bf(acc[i][j][r] + bvv[j]);
      }
    }
  } else if constexpr (EPI == 1){
    short* C = (short*)Cv;                       // vt[b][n][m_local], S=2048
    float bvv[4];
    #pragma unroll
    for (int j=0;j<4;j++) bvv[j] = bias0[nwb + j*16];
    #pragma unroll
    for (int i=0;i<8;i++){
      int m = mwb + i*16;
      int bidx = m >> 11, ml = m & 2047;
      #pragma unroll
      for (int j=0;j<4;j++){
        int n = nwb + j*16;
        short4v pk;
        #pragma unroll
        for (int r=0;r<4;r++) pk[r] = f2bf(acc[i][j][r] + bvv[j]);
        *(short4v*)&C[((size_t)(bidx*1024 + n)) * 2048 + ml] = pk;
      }
    }
  } else if constexpr (EPI == 2){
    short* C = (short*)Cv + (size_t)z * cbst;
    #pragma unroll
    for (int i=0;i<8;i++){
      int m = mwb + i*16;
      #pragma unroll
      for (int j=0;j<4;j++){
        int n = nwb + j*16;
        #pragma unroll
        for (int r=0;r<4;r++)
          C[(size_t)(m+r)*N + n] = f2bf(acc[i][j][r] * scale);
      }
    }
  } else {
    float* C = (float*)Cv + (size_t)z * cbst;
    #pragma unroll
    for (int i=0;i<8;i++){
      int m = mwb + i*16;
      #pragma unroll
      for (int j=0;j<4;j++){
        int n = nwb + j*16;
        #pragma unroll
        for (int r=0;r<4;r++)
          C[(size_t)(m+r)*N + n] = acc[i][j][r];
      }
    }
  }
}

// ---------------- row softmax, in-place on bf16 scores [rows][2048] ----------------
__global__ __launch_bounds__(256) void softmax_kernel(short* __restrict__ S){
  const int row = blockIdx.x;
  short* p = S + (size_t)row * 2048;
  const int t = threadIdx.x, w = t >> 6, l = t & 63;
  short8 v = *(short8*)&p[t*8];
  float f[8];
  #pragma unroll
  for (int i=0;i<8;i++) f[i] = bf2f(v[i]);
  float mx = f[0];
  #pragma unroll
  for (int i=1;i<8;i++) mx = fmaxf(mx, f[i]);
  #pragma unroll
  for (int off=32; off>=1; off>>=1) mx = fmaxf(mx, __shfl_xor(mx, off));
  __shared__ float rmax[4], rsum[4];
  if (l == 0) rmax[w] = mx;
  __syncthreads();
  mx = fmaxf(fmaxf(rmax[0], rmax[1]), fmaxf(rmax[2], rmax[3]));
  float e[8], s = 0.f;
  #pragma unroll
  for (int i=0;i<8;i++){ e[i] = __expf(f[i] - mx); s += e[i]; }
  #pragma unroll
  for (int off=32; off>=1; off>>=1) s += __shfl_xor(s, off);
  if (l == 0) rsum[w] = s;
  __syncthreads();
  s = rsum[0] + rsum[1] + rsum[2] + rsum[3];
  float inv = 1.0f / s;
  short8 o;
  #pragma unroll
  for (int i=0;i<8;i++) o[i] = f2bf(e[i] * inv);
  *(short8*)&p[t*8] = o;
}

// ---------------- launch ----------------
extern "C" void kernel_launch(void* const* d_in, const int* in_sizes, int n_in,
                              void* d_out, int out_size, void* d_ws, size_t ws_size,
                              hipStream_t stream){
  (void)in_sizes; (void)n_in; (void)out_size; (void)ws_size;
  const float* x  = (const float*)d_in[0];
  const float* Wq = (const float*)d_in[1];
  const float* bq = (const float*)d_in[2];
  const float* Wk = (const float*)d_in[3];
  const float* bk = (const float*)d_in[4];
  const float* Wv = (const float*)d_in[5];
  const float* bv = (const float*)d_in[6];
  float* out = (float*)d_out;
  char* ws = (char*)d_ws;

  // ws layout: qb@0 (32M), kb@32M, vt@64M, xb@96M (32M), Wt@128M (6M)
  // scores overlay xb after QKV: 32 MiB = one 4-batch group
  short* qb  = (short*)(ws + 0);
  short* kb  = (short*)(ws + 33554432);
  short* vt  = (short*)(ws + 67108864);
  short* xb  = (short*)(ws + 100663296);
  short* Wt  = (short*)(ws + 134217728);
  short* Sg  = xb;

  cvt_x_kernel<<<8192, 256, 0, stream>>>(x, xb);
  cvt_w_kernel<<<dim3(32,32,3), dim3(32,8), 0, stream>>>(Wq, Wk, Wv, Wt);

  // q and k: z in {0,1} (qb/kb adjacent: cbst = 16M shorts)
  gemm256<0><<<dim3(64,4,2), 512, 0, stream>>>(xb, 1024, 0L, Wt, 1024, 1048576L,
                                               qb, 16777216L, bq, bk, 16384, 1024, 1024, 1.f);
  // v, written transposed (reads xb — precedes scores overwriting it)
  gemm256<1><<<dim3(64,4,1), 512, 0, stream>>>(xb, 1024, 0L, Wt + 2*1048576, 1024, 0L,
                                               vt, 0L, bv, nullptr, 16384, 1024, 1024, 1.f);

  for (int g = 0; g < 2; g++){
    const size_t boff = (size_t)g * 4 * 2097152;   // 4 batches * S*D elements
    gemm256<2><<<dim3(8,8,4), 512, 0, stream>>>(qb + boff, 1024, 2097152L,
                                                kb + boff, 1024, 2097152L,
                                                Sg, 4194304L, nullptr, nullptr,
                                                2048, 2048, 1024, 0.03125f);
    softmax_kernel<<<8192, 256, 0, stream>>>(Sg);
    gemm256<3><<<dim3(8,4,4), 512, 0, stream>>>(Sg, 2048, 4194304L,
                                                vt + boff, 2048, 2097152L,
                                                out + boff, 2097152L, nullptr, nullptr,
                                                2048, 1024, 2048, 1.f);
  }
}